// Round 1
// baseline (592.204 us; speedup 1.0000x reference)
//
#include <hip/hip_runtime.h>
#include <math.h>

// Problem constants (fixed by setup_inputs)
#define BSZ   4
#define NTOK  6400      // h*w = 40*160
#define DMODEL 256
#define NHEAD 8
#define HDIM  32
#define NPTS  9
#define HSP   40
#define WSP   160
#define KDIM  256       // inner dim of all GEMMs

// ---------------------------------------------------------------------------
// Generic tiled fp32 GEMM:  Y = X @ W^T + bias,  X:(M,K) W:(Ncols,K) row-major
// MODE 0: plain store Y (M,Ncols)
// MODE 1: tanh(acc+bias)*4 store, with Ncols=144 bounds guard (offsets)
// MODE 2: Ncols=512, scatter cols<256 -> k_flat (B*H,N,32), cols>=256 -> v_flat
// ---------------------------------------------------------------------------
template <int MODE>
__global__ __launch_bounds__(256) void gemm_xt(
    const float* __restrict__ X,
    const float* __restrict__ W,
    const float* __restrict__ bias,
    float* __restrict__ Y,
    float* __restrict__ Y2,
    int M, int Ncols)
{
    const int BM = 64, BN = 64, BK = 32;
    __shared__ float As[BK][BM + 1];   // +1 pad: conflict-free transposed store
    __shared__ float Bs[BK][BN + 1];

    const int tid = threadIdx.x;
    const int block_m = blockIdx.y * BM;
    const int block_n = blockIdx.x * BN;

    const int lrow = tid / 8;          // 0..31
    const int lcol = (tid % 8) * 4;    // k offset, float4 granular

    const int ty = tid / 16;           // 0..15
    const int tx = tid % 16;           // 0..15

    float acc[4][4] = {};

    for (int k0 = 0; k0 < KDIM; k0 += BK) {
        // stage A tile (64 rows x 32 k)
        #pragma unroll
        for (int half = 0; half < 2; ++half) {
            int r = lrow + half * 32;
            int grow = block_m + r;
            float4 av = *(const float4*)(X + (size_t)grow * KDIM + k0 + lcol);
            As[lcol + 0][r] = av.x;
            As[lcol + 1][r] = av.y;
            As[lcol + 2][r] = av.z;
            As[lcol + 3][r] = av.w;
        }
        // stage B tile (64 out-cols x 32 k)
        #pragma unroll
        for (int half = 0; half < 2; ++half) {
            int r = lrow + half * 32;
            int gcol = block_n + r;
            float4 bv;
            if (MODE == 1 && gcol >= Ncols) bv = make_float4(0.f, 0.f, 0.f, 0.f);
            else bv = *(const float4*)(W + (size_t)gcol * KDIM + k0 + lcol);
            Bs[lcol + 0][r] = bv.x;
            Bs[lcol + 1][r] = bv.y;
            Bs[lcol + 2][r] = bv.z;
            Bs[lcol + 3][r] = bv.w;
        }
        __syncthreads();

        #pragma unroll
        for (int k = 0; k < BK; ++k) {
            float am[4], bn[4];
            #pragma unroll
            for (int i = 0; i < 4; ++i) am[i] = As[k][ty * 4 + i];
            #pragma unroll
            for (int j = 0; j < 4; ++j) bn[j] = Bs[k][tx * 4 + j];
            #pragma unroll
            for (int i = 0; i < 4; ++i)
                #pragma unroll
                for (int j = 0; j < 4; ++j)
                    acc[i][j] = fmaf(am[i], bn[j], acc[i][j]);
        }
        __syncthreads();
    }

    // epilogue
    #pragma unroll
    for (int i = 0; i < 4; ++i) {
        const int grow = block_m + ty * 4 + i;
        #pragma unroll
        for (int j = 0; j < 4; ++j) {
            const int gcol = block_n + tx * 4 + j;
            if (MODE == 1 && gcol >= Ncols) continue;
            float val = acc[i][j] + bias[gcol];
            if (MODE == 0) {
                Y[(size_t)grow * Ncols + gcol] = val;
            } else if (MODE == 1) {
                Y[(size_t)grow * Ncols + gcol] = tanhf(val) * 4.0f;  // fold OFFSET_SCALE
            } else {  // MODE 2: kv scatter into (B*H, N, 32)
                const int b = grow / NTOK;
                const int n = grow % NTOK;
                if (gcol < DMODEL) {
                    const int hh = gcol >> 5, c = gcol & 31;
                    Y[(((size_t)(b * NHEAD + hh)) * NTOK + n) * HDIM + c] = val;
                } else {
                    const int g2 = gcol - DMODEL;
                    const int hh = g2 >> 5, c = g2 & 31;
                    Y2[(((size_t)(b * NHEAD + hh)) * NTOK + n) * HDIM + c] = val;
                }
            }
        }
    }
}

// ---------------------------------------------------------------------------
// Deformable sampling + 9-point softmax attention.
// One block per (b, n); wave = 2 heads x 32 channels. Writes (B,N,256) layout
// IN PLACE over the q buffer (same index per thread; read-before-write safe).
// ---------------------------------------------------------------------------
__global__ __launch_bounds__(256) void deform_attn(
    const float* __restrict__ q,     // (B,N,256)
    const float* __restrict__ off,   // (B,N,144), tanh*4 already applied
    const float* __restrict__ kf,    // (B*H, N, 32)
    const float* __restrict__ vf,    // (B*H, N, 32)
    float* __restrict__ out)         // (B,N,256)  (aliases q)
{
    const int bn = blockIdx.x;
    const int b = bn / NTOK, n = bn % NTOK;
    const int wave = threadIdx.x >> 6;
    const int lane = threadIdx.x & 63;
    const int h = wave * 2 + (lane >> 5);
    const int c = lane & 31;

    const float qc = q[(size_t)bn * DMODEL + h * HDIM + c];
    const float* ob = off + (size_t)bn * (NHEAD * NPTS * 2) + h * (NPTS * 2);
    const float basex = (float)(n % WSP);
    const float basey = (float)(n / WSP);
    const float* kb = kf + ((size_t)(b * NHEAD + h)) * NTOK * HDIM;
    const float* vb = vf + ((size_t)(b * NHEAD + h)) * NTOK * HDIM;

    float logit[NPTS], vsamp[NPTS];

    #pragma unroll
    for (int p = 0; p < NPTS; ++p) {
        const float sx = basex + ob[p * 2 + 0];
        const float sy = basey + ob[p * 2 + 1];
        const float fx0 = floorf(sx), fy0 = floorf(sy);
        const float wx1 = sx - fx0, wx0 = 1.0f - wx1;
        const float wy1 = sy - fy0, wy0 = 1.0f - wy1;
        const int ix0 = (int)fx0, iy0 = (int)fy0;
        const int ix1 = ix0 + 1, iy1 = iy0 + 1;
        const bool vx0 = (ix0 >= 0) && (ix0 <= WSP - 1);
        const bool vx1 = (ix1 >= 0) && (ix1 <= WSP - 1);
        const bool vy0 = (iy0 >= 0) && (iy0 <= HSP - 1);
        const bool vy1 = (iy1 >= 0) && (iy1 <= HSP - 1);
        const int cx0 = min(max(ix0, 0), WSP - 1);
        const int cx1 = min(max(ix1, 0), WSP - 1);
        const int cy0 = min(max(iy0, 0), HSP - 1);
        const int cy1 = min(max(iy1, 0), HSP - 1);
        const float w00 = wx0 * wy0 * (float)(vx0 && vy0);
        const float w10 = wx1 * wy0 * (float)(vx1 && vy0);
        const float w01 = wx0 * wy1 * (float)(vx0 && vy1);
        const float w11 = wx1 * wy1 * (float)(vx1 && vy1);
        const int i00 = (cy0 * WSP + cx0) * HDIM + c;
        const int i10 = (cy0 * WSP + cx1) * HDIM + c;
        const int i01 = (cy1 * WSP + cx0) * HDIM + c;
        const int i11 = (cy1 * WSP + cx1) * HDIM + c;

        const float ks = w00 * kb[i00] + w10 * kb[i10] + w01 * kb[i01] + w11 * kb[i11];
        vsamp[p]       = w00 * vb[i00] + w10 * vb[i10] + w01 * vb[i01] + w11 * vb[i11];

        float l = qc * ks;
        #pragma unroll
        for (int o = 16; o >= 1; o >>= 1) l += __shfl_xor(l, o, 64);  // 32-lane reduce
        logit[p] = l * 0.17677669529663687f;  // hd^-0.5
    }

    // softmax over 9 points (every lane holds identical logits for its head)
    float m = logit[0];
    #pragma unroll
    for (int p = 1; p < NPTS; ++p) m = fmaxf(m, logit[p]);
    float e[NPTS], s = 0.f;
    #pragma unroll
    for (int p = 0; p < NPTS; ++p) { e[p] = expf(logit[p] - m); s += e[p]; }
    const float inv = 1.0f / s;

    float oc = 0.f;
    #pragma unroll
    for (int p = 0; p < NPTS; ++p) oc = fmaf(e[p] * inv, vsamp[p], oc);

    out[(size_t)bn * DMODEL + h * HDIM + c] = oc;
}

// ---------------------------------------------------------------------------
extern "C" void kernel_launch(void* const* d_in, const int* in_sizes, int n_in,
                              void* d_out, int out_size, void* d_ws, size_t ws_size,
                              hipStream_t stream) {
    const float* x    = (const float*)d_in[0];
    const float* Wq   = (const float*)d_in[1];
    const float* bq   = (const float*)d_in[2];
    const float* Woff = (const float*)d_in[3];
    const float* boff = (const float*)d_in[4];
    const float* Wkv  = (const float*)d_in[5];
    const float* bkv  = (const float*)d_in[6];
    const float* Wout = (const float*)d_in[7];
    const float* bout = (const float*)d_in[8];

    const int M = BSZ * NTOK;  // 25600

    float* ws   = (float*)d_ws;
    float* q    = ws;                                   // M*256 = 6.55M floats
    float* off  = q   + (size_t)M * DMODEL;             // M*144
    float* kf   = off + (size_t)M * (NHEAD * NPTS * 2); // 32*6400*32
    float* vf   = kf  + (size_t)BSZ * NHEAD * NTOK * HDIM;
    float* attn = q;                                    // in-place over q

    dim3 blk(256);
    gemm_xt<0><<<dim3(DMODEL / 64, M / 64), blk, 0, stream>>>(x, Wq, bq, q, nullptr, M, DMODEL);
    gemm_xt<1><<<dim3(3, M / 64), blk, 0, stream>>>(x, Woff, boff, off, nullptr, M, NHEAD * NPTS * 2);
    gemm_xt<2><<<dim3(8, M / 64), blk, 0, stream>>>(x, Wkv, bkv, kf, vf, M, 2 * DMODEL);
    deform_attn<<<dim3(M), blk, 0, stream>>>(q, off, kf, vf, attn);
    gemm_xt<0><<<dim3(DMODEL / 64, M / 64), blk, 0, stream>>>(attn, Wout, bout, (float*)d_out, nullptr, M, DMODEL);
}

// Round 2
// 231.440 us; speedup vs baseline: 2.5588x; 2.5588x over previous
//
#include <hip/hip_runtime.h>
#include <math.h>

#define BSZ    4
#define NTOK   6400      // 40*160
#define DMODEL 256
#define NHEAD  8
#define HDIM   32
#define NPTS   9
#define HSP    40
#define WSP    160
#define KDIM   256
#define MTOT   (BSZ*NTOK)   // 25600

typedef short  short8  __attribute__((ext_vector_type(8)));
typedef float  floatx4 __attribute__((ext_vector_type(4)));

__device__ __forceinline__ ushort f2bf(float f) {
    uint u = __float_as_uint(f);
    u = (u + 0x7FFFu + ((u >> 16) & 1u)) >> 16;   // RNE
    return (ushort)u;
}
__device__ __forceinline__ float bf2f(ushort u) {
    return __uint_as_float(((uint)u) << 16);
}

// ---------------------------------------------------------------------------
// fp32 -> bf16 cast, 4 elems/thread, exact grids
// ---------------------------------------------------------------------------
__global__ __launch_bounds__(256) void cast_bf16(const float* __restrict__ in,
                                                 ushort* __restrict__ out) {
    const int i = (blockIdx.x * 256 + threadIdx.x) * 4;
    float4 v = *(const float4*)(in + i);
    ushort4 o;
    o.x = f2bf(v.x); o.y = f2bf(v.y); o.z = f2bf(v.z); o.w = f2bf(v.w);
    *(ushort4*)(out + i) = o;
}

// ---------------------------------------------------------------------------
// bf16 MFMA GEMM:  Y = Xb @ Wb^T + bias.  Xb:(M,256), Wb:(Ncols,256) bf16.
// 128x128 tile, 256 thr = 4 waves (2x2), each wave 64x64 = 4x4 frags 16x16x32.
// MODE 0: store bf16 (M,256)              (q)
// MODE 1: store fp32 tanh(v)*4, Ncols=144 (offsets)
// MODE 2: Ncols=512 scatter bf16 -> k_flat / v_flat (B*H,N,32)
// MODE 3: store fp32 (M,256)              (final out)
// ---------------------------------------------------------------------------
template <int MODE>
__global__ __launch_bounds__(256) void gemm_bf16(
    const ushort* __restrict__ Xb,
    const ushort* __restrict__ Wb,
    const float* __restrict__ bias,
    void* __restrict__ Yv, void* __restrict__ Y2v,
    int Ncols)
{
    __shared__ ushort As[128][40];   // 32 k + 8 pad -> 2-way (free) b128 pattern
    __shared__ ushort Bs[128][40];

    const int tid = threadIdx.x;
    const int block_m = blockIdx.y * 128;
    const int block_n = blockIdx.x * 128;
    const int wave = tid >> 6, lane = tid & 63;
    const int wm = (wave >> 1) * 64, wn = (wave & 1) * 64;
    const int l15 = lane & 15, quad = lane >> 4;

    const int srow = tid >> 2;        // 0..63
    const int scol = (tid & 3) * 8;   // 0,8,16,24

    floatx4 acc[4][4];
    #pragma unroll
    for (int i = 0; i < 4; ++i)
        #pragma unroll
        for (int j = 0; j < 4; ++j) {
            acc[i][j][0] = 0.f; acc[i][j][1] = 0.f;
            acc[i][j][2] = 0.f; acc[i][j][3] = 0.f;
        }

    for (int k0 = 0; k0 < KDIM; k0 += 32) {
        #pragma unroll
        for (int half = 0; half < 2; ++half) {
            const int r = srow + half * 64;
            uint4 av = *(const uint4*)(Xb + (size_t)(block_m + r) * KDIM + k0 + scol);
            *(uint4*)&As[r][scol] = av;
            const int gcol = block_n + r;
            uint4 bv;
            if (MODE == 1 && gcol >= Ncols) bv = make_uint4(0u, 0u, 0u, 0u);
            else bv = *(const uint4*)(Wb + (size_t)gcol * KDIM + k0 + scol);
            *(uint4*)&Bs[r][scol] = bv;
        }
        __syncthreads();

        short8 af[4], bfr[4];
        #pragma unroll
        for (int f = 0; f < 4; ++f) {
            af[f]  = *(const short8*)&As[wm + f * 16 + l15][quad * 8];
            bfr[f] = *(const short8*)&Bs[wn + f * 16 + l15][quad * 8];
        }
        #pragma unroll
        for (int fm = 0; fm < 4; ++fm)
            #pragma unroll
            for (int fn = 0; fn < 4; ++fn)
                acc[fm][fn] = __builtin_amdgcn_mfma_f32_16x16x32_bf16(
                    af[fm], bfr[fn], acc[fm][fn], 0, 0, 0);
        __syncthreads();
    }

    // epilogue: C/D layout col=lane&15, row=quad*4+reg (m89/m91-verified)
    #pragma unroll
    for (int fn = 0; fn < 4; ++fn) {
        const int col = block_n + wn + fn * 16 + l15;
        const float bcol = (MODE == 1 && col >= Ncols) ? 0.f : bias[col];
        #pragma unroll
        for (int fm = 0; fm < 4; ++fm) {
            #pragma unroll
            for (int r = 0; r < 4; ++r) {
                const int row = block_m + wm + fm * 16 + quad * 4 + r;
                const float val = acc[fm][fn][r] + bcol;
                if (MODE == 0) {
                    ((ushort*)Yv)[(size_t)row * DMODEL + col] = f2bf(val);
                } else if (MODE == 1) {
                    if (col < Ncols)
                        ((float*)Yv)[(size_t)row * 144 + col] = tanhf(val) * 4.0f;
                } else if (MODE == 2) {
                    const int b = row / NTOK, n = row % NTOK;
                    const int hh = (col & 255) >> 5, c = col & 31;
                    const size_t o = (((size_t)(b * NHEAD + hh)) * NTOK + n) * HDIM + c;
                    if (col < DMODEL) ((ushort*)Yv)[o]  = f2bf(val);
                    else              ((ushort*)Y2v)[o] = f2bf(val);
                } else {
                    ((float*)Yv)[(size_t)row * DMODEL + col] = val;
                }
            }
        }
    }
}

// ---------------------------------------------------------------------------
// Deformable sampling + softmax attention. One wave per token: 8 heads x
// (8 lanes x float4 channels). bf16 q/k/v in, bf16 attn out, fp32 math.
// ---------------------------------------------------------------------------
__global__ __launch_bounds__(256) void deform_attn(
    const ushort* __restrict__ qb,    // (M,256) bf16
    const float* __restrict__ off,    // (M,144) fp32 (tanh*4 applied)
    const ushort* __restrict__ kfb,   // (B*H,N,32) bf16
    const ushort* __restrict__ vfb,
    ushort* __restrict__ attnb)       // (M,256) bf16
{
    const int token = blockIdx.x * 4 + (threadIdx.x >> 6);
    const int lane = threadIdx.x & 63;
    const int h = lane >> 3, lc = lane & 7;
    const int b = token / NTOK, n = token % NTOK;

    const ushort4 qu = *(const ushort4*)(qb + (size_t)token * DMODEL + h * HDIM + lc * 4);
    const float q0 = bf2f(qu.x), q1 = bf2f(qu.y), q2 = bf2f(qu.z), q3 = bf2f(qu.w);

    const float* ob = off + (size_t)token * 144 + h * (NPTS * 2);
    const float bx = (float)(n % WSP), by = (float)(n / WSP);
    const ushort* kb = kfb + (size_t)(b * NHEAD + h) * NTOK * HDIM;
    const ushort* vb = vfb + (size_t)(b * NHEAD + h) * NTOK * HDIM;

    float vs[NPTS][4];
    float logit[NPTS];

    #pragma unroll
    for (int p = 0; p < NPTS; ++p) {
        const float sx = bx + ob[p * 2 + 0];
        const float sy = by + ob[p * 2 + 1];
        const float fx0 = floorf(sx), fy0 = floorf(sy);
        const float wx1 = sx - fx0, wx0 = 1.0f - wx1;
        const float wy1 = sy - fy0, wy0 = 1.0f - wy1;
        const int ix0 = (int)fx0, iy0 = (int)fy0;
        const int ix1 = ix0 + 1, iy1 = iy0 + 1;
        const bool vx0 = (ix0 >= 0) & (ix0 <= WSP - 1);
        const bool vx1 = (ix1 >= 0) & (ix1 <= WSP - 1);
        const bool vy0 = (iy0 >= 0) & (iy0 <= HSP - 1);
        const bool vy1 = (iy1 >= 0) & (iy1 <= HSP - 1);
        const int cx0 = min(max(ix0, 0), WSP - 1);
        const int cx1 = min(max(ix1, 0), WSP - 1);
        const int cy0 = min(max(iy0, 0), HSP - 1);
        const int cy1 = min(max(iy1, 0), HSP - 1);
        const float w00 = wx0 * wy0 * (float)(vx0 && vy0);
        const float w10 = wx1 * wy0 * (float)(vx1 && vy0);
        const float w01 = wx0 * wy1 * (float)(vx0 && vy1);
        const float w11 = wx1 * wy1 * (float)(vx1 && vy1);
        const int i00 = (cy0 * WSP + cx0) * HDIM + lc * 4;
        const int i10 = (cy0 * WSP + cx1) * HDIM + lc * 4;
        const int i01 = (cy1 * WSP + cx0) * HDIM + lc * 4;
        const int i11 = (cy1 * WSP + cx1) * HDIM + lc * 4;

        const ushort4 k00 = *(const ushort4*)(kb + i00);
        const ushort4 k10 = *(const ushort4*)(kb + i10);
        const ushort4 k01 = *(const ushort4*)(kb + i01);
        const ushort4 k11 = *(const ushort4*)(kb + i11);
        const ushort4 v00 = *(const ushort4*)(vb + i00);
        const ushort4 v10 = *(const ushort4*)(vb + i10);
        const ushort4 v01 = *(const ushort4*)(vb + i01);
        const ushort4 v11 = *(const ushort4*)(vb + i11);

        const float ks0 = w00*bf2f(k00.x) + w10*bf2f(k10.x) + w01*bf2f(k01.x) + w11*bf2f(k11.x);
        const float ks1 = w00*bf2f(k00.y) + w10*bf2f(k10.y) + w01*bf2f(k01.y) + w11*bf2f(k11.y);
        const float ks2 = w00*bf2f(k00.z) + w10*bf2f(k10.z) + w01*bf2f(k01.z) + w11*bf2f(k11.z);
        const float ks3 = w00*bf2f(k00.w) + w10*bf2f(k10.w) + w01*bf2f(k01.w) + w11*bf2f(k11.w);
        vs[p][0] = w00*bf2f(v00.x) + w10*bf2f(v10.x) + w01*bf2f(v01.x) + w11*bf2f(v11.x);
        vs[p][1] = w00*bf2f(v00.y) + w10*bf2f(v10.y) + w01*bf2f(v01.y) + w11*bf2f(v11.y);
        vs[p][2] = w00*bf2f(v00.z) + w10*bf2f(v10.z) + w01*bf2f(v01.z) + w11*bf2f(v11.z);
        vs[p][3] = w00*bf2f(v00.w) + w10*bf2f(v10.w) + w01*bf2f(v01.w) + w11*bf2f(v11.w);

        float part = q0*ks0 + q1*ks1 + q2*ks2 + q3*ks3;
        part += __shfl_xor(part, 1, 64);
        part += __shfl_xor(part, 2, 64);
        part += __shfl_xor(part, 4, 64);
        logit[p] = part * 0.17677669529663687f;   // 32^-0.5
    }

    float m = logit[0];
    #pragma unroll
    for (int p = 1; p < NPTS; ++p) m = fmaxf(m, logit[p]);
    float e[NPTS], s = 0.f;
    #pragma unroll
    for (int p = 0; p < NPTS; ++p) { e[p] = __expf(logit[p] - m); s += e[p]; }
    const float inv = 1.0f / s;

    float o0 = 0.f, o1 = 0.f, o2 = 0.f, o3 = 0.f;
    #pragma unroll
    for (int p = 0; p < NPTS; ++p) {
        const float wgt = e[p] * inv;
        o0 = fmaf(wgt, vs[p][0], o0);
        o1 = fmaf(wgt, vs[p][1], o1);
        o2 = fmaf(wgt, vs[p][2], o2);
        o3 = fmaf(wgt, vs[p][3], o3);
    }

    ushort4 ou;
    ou.x = f2bf(o0); ou.y = f2bf(o1); ou.z = f2bf(o2); ou.w = f2bf(o3);
    *(ushort4*)(attnb + (size_t)token * DMODEL + h * HDIM + lc * 4) = ou;
}

// ---------------------------------------------------------------------------
extern "C" void kernel_launch(void* const* d_in, const int* in_sizes, int n_in,
                              void* d_out, int out_size, void* d_ws, size_t ws_size,
                              hipStream_t stream) {
    const float* x    = (const float*)d_in[0];
    const float* Wq   = (const float*)d_in[1];
    const float* bq   = (const float*)d_in[2];
    const float* Woff = (const float*)d_in[3];
    const float* boff = (const float*)d_in[4];
    const float* Wkv  = (const float*)d_in[5];
    const float* bkv  = (const float*)d_in[6];
    const float* Wout = (const float*)d_in[7];
    const float* bout = (const float*)d_in[8];

    // workspace layout (81 MB total, all 16B-aligned)
    ushort* xb    = (ushort*)d_ws;                         // 6,553,600
    ushort* qb    = xb + (size_t)MTOT * DMODEL;            // 6,553,600
    float*  off   = (float*)(qb + (size_t)MTOT * DMODEL);  // 3,686,400 fp32
    ushort* kfb   = (ushort*)(off + (size_t)MTOT * 144);   // 6,553,600
    ushort* vfb   = kfb + (size_t)MTOT * DMODEL;           // 6,553,600
    ushort* attnb = vfb + (size_t)MTOT * DMODEL;           // 6,553,600
    ushort* wqb   = attnb + (size_t)MTOT * DMODEL;         // 65,536
    ushort* woffb = wqb + 65536;                           // 36,864
    ushort* wkvb  = woffb + 36864;                         // 131,072
    ushort* woutb = wkvb + 131072;                         // 65,536

    cast_bf16<<<dim3(6400), dim3(256), 0, stream>>>(x, xb);
    cast_bf16<<<dim3(64),   dim3(256), 0, stream>>>(Wq, wqb);
    cast_bf16<<<dim3(36),   dim3(256), 0, stream>>>(Woff, woffb);
    cast_bf16<<<dim3(128),  dim3(256), 0, stream>>>(Wkv, wkvb);
    cast_bf16<<<dim3(64),   dim3(256), 0, stream>>>(Wout, woutb);

    gemm_bf16<0><<<dim3(2, 200), dim3(256), 0, stream>>>(xb, wqb, bq, qb, nullptr, 256);
    gemm_bf16<1><<<dim3(2, 200), dim3(256), 0, stream>>>(xb, woffb, boff, off, nullptr, 144);
    gemm_bf16<2><<<dim3(4, 200), dim3(256), 0, stream>>>(xb, wkvb, bkv, kfb, vfb, 512);
    deform_attn<<<dim3(6400), dim3(256), 0, stream>>>(qb, off, kfb, vfb, attnb);
    gemm_bf16<3><<<dim3(2, 200), dim3(256), 0, stream>>>(attnb, woutb, bout, d_out, nullptr, 256);
}

// Round 3
// 215.260 us; speedup vs baseline: 2.7511x; 1.0752x over previous
//
#include <hip/hip_runtime.h>
#include <math.h>

#define BSZ    4
#define NTOK   6400      // 40*160
#define DMODEL 256
#define NHEAD  8
#define HDIM   32
#define NPTS   9
#define HSP    40
#define WSP    160
#define KDIM   256
#define MTOT   (BSZ*NTOK)   // 25600

typedef short  short8  __attribute__((ext_vector_type(8)));
typedef float  floatx4 __attribute__((ext_vector_type(4)));

__device__ __forceinline__ ushort f2bf(float f) {
    uint u = __float_as_uint(f);
    u = (u + 0x7FFFu + ((u >> 16) & 1u)) >> 16;   // RNE
    return (ushort)u;
}

// unpack 8 packed bf16 (uint4) -> 8 fp32, 1 VALU/elem
__device__ __forceinline__ void unpack8(uint4 u, float* f) {
    f[0] = __uint_as_float(u.x << 16); f[1] = __uint_as_float(u.x & 0xFFFF0000u);
    f[2] = __uint_as_float(u.y << 16); f[3] = __uint_as_float(u.y & 0xFFFF0000u);
    f[4] = __uint_as_float(u.z << 16); f[5] = __uint_as_float(u.z & 0xFFFF0000u);
    f[6] = __uint_as_float(u.w << 16); f[7] = __uint_as_float(u.w & 0xFFFF0000u);
}

#define AS1C(p) ((const __attribute__((address_space(1))) void*)(p))
#define AS3(p)  ((__attribute__((address_space(3))) void*)(p))

// ---------------------------------------------------------------------------
// All fp32->bf16 casts in one launch. Block = 1024 elems.
// ranges: x 6400 | Wq 64 | Woff 36 | Wkv 128 | Wout 64  => 6692 blocks
// ---------------------------------------------------------------------------
__global__ __launch_bounds__(256) void cast_all(
    const float* __restrict__ x,   const float* __restrict__ Wq,
    const float* __restrict__ Woff,const float* __restrict__ Wkv,
    const float* __restrict__ Wout,
    ushort* __restrict__ xb, ushort* __restrict__ wqb, ushort* __restrict__ woffb,
    ushort* __restrict__ wkvb, ushort* __restrict__ woutb)
{
    const int bid = blockIdx.x;
    const float* src; ushort* dst; int base;
    if      (bid < 6400) { src = x;    dst = xb;    base = bid; }
    else if (bid < 6464) { src = Wq;   dst = wqb;   base = bid - 6400; }
    else if (bid < 6500) { src = Woff; dst = woffb; base = bid - 6464; }
    else if (bid < 6628) { src = Wkv;  dst = wkvb;  base = bid - 6500; }
    else                 { src = Wout; dst = woutb; base = bid - 6628; }
    const int i = base * 1024 + threadIdx.x * 4;
    float4 v = *(const float4*)(src + i);
    ushort4 o;
    o.x = f2bf(v.x); o.y = f2bf(v.y); o.z = f2bf(v.z); o.w = f2bf(v.w);
    *(ushort4*)(dst + i) = o;
}

// ---------------------------------------------------------------------------
// bf16 MFMA GEMM, m97-style global_load_lds(16B) staging, 128x128 tile.
// LDS [128][32] ushort unpadded (2-way bank aliasing = free).
// MODE 0: store bf16 (M,256)              (q)
// MODE 1: store fp32 tanh(v)*4, Ncols=144 (offsets)
// MODE 2: Ncols=512 scatter bf16 -> k_flat / v_flat (B*H,N,32)
// MODE 3: store fp32 (M,256)              (final out)
// ---------------------------------------------------------------------------
template <int MODE>
__global__ __launch_bounds__(256) void gemm_bf16(
    const ushort* __restrict__ Xb,
    const ushort* __restrict__ Wb,
    const float* __restrict__ bias,
    void* __restrict__ Yv, void* __restrict__ Y2v,
    int Ncols)
{
    __shared__ ushort As[128 * 32];
    __shared__ ushort Bs[128 * 32];

    const int tid = threadIdx.x;
    const int block_m = blockIdx.y * 128;
    const int block_n = blockIdx.x * 128;
    const int wave = tid >> 6, lane = tid & 63;
    const int wm = (wave >> 1) * 64, wn = (wave & 1) * 64;
    const int l15 = lane & 15, quad = lane >> 4;

    // staging map: wave w covers rows [w*32, w*32+32); lane l -> row w*32+s*16+l/4,
    // col ushort (l&3)*8 == LDS byte (seg base + l*16). Wave-uniform LDS base.
    const int srow = wave * 32 + (lane >> 2);
    const int scol = (lane & 3) * 8;

    const ushort* gA0 = Xb + (size_t)(block_m + srow) * KDIM + scol;
    const ushort* gA1 = gA0 + 16 * KDIM;
    int bc0 = block_n + srow, bc1 = bc0 + 16;
    if (MODE == 1) { bc0 = min(bc0, Ncols - 1); bc1 = min(bc1, Ncols - 1); }
    const ushort* gB0 = Wb + (size_t)bc0 * KDIM + scol;
    const ushort* gB1 = Wb + (size_t)bc1 * KDIM + scol;

    ushort* lA0 = &As[(wave * 32) * 32];
    ushort* lA1 = &As[(wave * 32 + 16) * 32];
    ushort* lB0 = &Bs[(wave * 32) * 32];
    ushort* lB1 = &Bs[(wave * 32 + 16) * 32];

    floatx4 acc[4][4];
    #pragma unroll
    for (int i = 0; i < 4; ++i)
        #pragma unroll
        for (int j = 0; j < 4; ++j) {
            acc[i][j][0] = 0.f; acc[i][j][1] = 0.f;
            acc[i][j][2] = 0.f; acc[i][j][3] = 0.f;
        }

    for (int k0 = 0; k0 < KDIM; k0 += 32) {
        __builtin_amdgcn_global_load_lds(AS1C(gA0 + k0), AS3(lA0), 16, 0, 0);
        __builtin_amdgcn_global_load_lds(AS1C(gA1 + k0), AS3(lA1), 16, 0, 0);
        __builtin_amdgcn_global_load_lds(AS1C(gB0 + k0), AS3(lB0), 16, 0, 0);
        __builtin_amdgcn_global_load_lds(AS1C(gB1 + k0), AS3(lB1), 16, 0, 0);
        __syncthreads();

        short8 af[4], bfr[4];
        #pragma unroll
        for (int f = 0; f < 4; ++f) {
            af[f]  = *(const short8*)&As[(wm + f * 16 + l15) * 32 + quad * 8];
            bfr[f] = *(const short8*)&Bs[(wn + f * 16 + l15) * 32 + quad * 8];
        }
        #pragma unroll
        for (int fm = 0; fm < 4; ++fm)
            #pragma unroll
            for (int fn = 0; fn < 4; ++fn)
                acc[fm][fn] = __builtin_amdgcn_mfma_f32_16x16x32_bf16(
                    af[fm], bfr[fn], acc[fm][fn], 0, 0, 0);
        __syncthreads();
    }

    // epilogue: C/D layout col=lane&15, row=quad*4+reg
    #pragma unroll
    for (int fn = 0; fn < 4; ++fn) {
        const int col = block_n + wn + fn * 16 + l15;
        const float bcol = (MODE == 1 && col >= Ncols) ? 0.f : bias[col];
        #pragma unroll
        for (int fm = 0; fm < 4; ++fm) {
            #pragma unroll
            for (int r = 0; r < 4; ++r) {
                const int row = block_m + wm + fm * 16 + quad * 4 + r;
                const float val = acc[fm][fn][r] + bcol;
                if (MODE == 0) {
                    ((ushort*)Yv)[(size_t)row * DMODEL + col] = f2bf(val);
                } else if (MODE == 1) {
                    if (col < Ncols)
                        ((float*)Yv)[(size_t)row * 144 + col] = tanhf(val) * 4.0f;
                } else if (MODE == 2) {
                    const int b = row / NTOK, n = row % NTOK;
                    const int hh = (col & 255) >> 5, c = col & 31;
                    const size_t o = (((size_t)(b * NHEAD + hh)) * NTOK + n) * HDIM + c;
                    if (col < DMODEL) ((ushort*)Yv)[o]  = f2bf(val);
                    else              ((ushort*)Y2v)[o] = f2bf(val);
                } else {
                    ((float*)Yv)[(size_t)row * DMODEL + col] = val;
                }
            }
        }
    }
}

// ---------------------------------------------------------------------------
// Deformable sampling + online-softmax attention.
// Wave = 2 tokens x 8 heads x 4 lanes; each lane owns 8 channels (16B loads).
// bf16 q/k/v in (1-inst unpack), fp32 math, bf16 out.
// ---------------------------------------------------------------------------
__global__ __launch_bounds__(256) void deform_attn(
    const ushort* __restrict__ qb,    // (M,256) bf16
    const float* __restrict__ off,    // (M,144) fp32 (tanh*4 applied)
    const ushort* __restrict__ kfb,   // (B*H,N,32) bf16
    const ushort* __restrict__ vfb,
    ushort* __restrict__ attnb)       // (M,256) bf16
{
    const int lane = threadIdx.x & 63;
    const int token = blockIdx.x * 8 + (threadIdx.x >> 6) * 2 + (lane >> 5);
    const int h = (lane >> 2) & 7, lc = lane & 3;
    const int b = token / NTOK, n = token % NTOK;

    const uint4 qu = *(const uint4*)(qb + (size_t)token * DMODEL + h * HDIM + lc * 8);
    float q[8]; unpack8(qu, q);

    const float* ob = off + (size_t)token * 144 + h * (NPTS * 2);
    float2 offs[NPTS];
    #pragma unroll
    for (int p = 0; p < NPTS; ++p) offs[p] = *(const float2*)(ob + 2 * p);

    const float bx = (float)(n % WSP), by = (float)(n / WSP);
    const ushort* kb = kfb + (size_t)(b * NHEAD + h) * NTOK * HDIM + lc * 8;
    const ushort* vb = vfb + (size_t)(b * NHEAD + h) * NTOK * HDIM + lc * 8;

    float m = -INFINITY, s = 0.f;
    float o[8];
    #pragma unroll
    for (int c = 0; c < 8; ++c) o[c] = 0.f;

    #pragma unroll
    for (int p = 0; p < NPTS; ++p) {
        const float sx = bx + offs[p].x, sy = by + offs[p].y;
        const float fx0 = floorf(sx), fy0 = floorf(sy);
        const float wx1 = sx - fx0, wx0 = 1.0f - wx1;
        const float wy1 = sy - fy0, wy0 = 1.0f - wy1;
        const int ix0 = (int)fx0, iy0 = (int)fy0;
        const int ix1 = ix0 + 1, iy1 = iy0 + 1;
        const bool vx0 = (ix0 >= 0) & (ix0 <= WSP - 1);
        const bool vx1 = (ix1 >= 0) & (ix1 <= WSP - 1);
        const bool vy0 = (iy0 >= 0) & (iy0 <= HSP - 1);
        const bool vy1 = (iy1 >= 0) & (iy1 <= HSP - 1);
        const int cx0 = min(max(ix0, 0), WSP - 1);
        const int cx1 = min(max(ix1, 0), WSP - 1);
        const int cy0 = min(max(iy0, 0), HSP - 1);
        const int cy1 = min(max(iy1, 0), HSP - 1);
        const float w00 = wx0 * wy0 * (float)(vx0 && vy0);
        const float w10 = wx1 * wy0 * (float)(vx1 && vy0);
        const float w01 = wx0 * wy1 * (float)(vx0 && vy1);
        const float w11 = wx1 * wy1 * (float)(vx1 && vy1);
        const int i00 = (cy0 * WSP + cx0) * HDIM;
        const int i10 = (cy0 * WSP + cx1) * HDIM;
        const int i01 = (cy1 * WSP + cx0) * HDIM;
        const int i11 = (cy1 * WSP + cx1) * HDIM;

        const uint4 ku0 = *(const uint4*)(kb + i00);
        const uint4 ku1 = *(const uint4*)(kb + i10);
        const uint4 ku2 = *(const uint4*)(kb + i01);
        const uint4 ku3 = *(const uint4*)(kb + i11);
        const uint4 vu0 = *(const uint4*)(vb + i00);
        const uint4 vu1 = *(const uint4*)(vb + i10);
        const uint4 vu2 = *(const uint4*)(vb + i01);
        const uint4 vu3 = *(const uint4*)(vb + i11);

        float kc[8], d00 = 0.f, d10 = 0.f, d01 = 0.f, d11 = 0.f;
        unpack8(ku0, kc);
        #pragma unroll
        for (int c = 0; c < 8; ++c) d00 = fmaf(q[c], kc[c], d00);
        unpack8(ku1, kc);
        #pragma unroll
        for (int c = 0; c < 8; ++c) d10 = fmaf(q[c], kc[c], d10);
        unpack8(ku2, kc);
        #pragma unroll
        for (int c = 0; c < 8; ++c) d01 = fmaf(q[c], kc[c], d01);
        unpack8(ku3, kc);
        #pragma unroll
        for (int c = 0; c < 8; ++c) d11 = fmaf(q[c], kc[c], d11);

        float part = w00 * d00 + w10 * d10 + w01 * d01 + w11 * d11;
        part += __shfl_xor(part, 1, 64);
        part += __shfl_xor(part, 2, 64);
        const float l = part * 0.17677669529663687f;   // 32^-0.5

        const float m1 = fmaxf(m, l);
        const float corr = __expf(m - m1);
        const float e = __expf(l - m1);
        s = fmaf(s, corr, e);
        m = m1;

        const float e00 = e * w00, e10 = e * w10, e01 = e * w01, e11 = e * w11;
        float v0[8], v1[8], v2[8], v3[8];
        unpack8(vu0, v0); unpack8(vu1, v1); unpack8(vu2, v2); unpack8(vu3, v3);
        #pragma unroll
        for (int c = 0; c < 8; ++c)
            o[c] = fmaf(o[c], corr,
                        fmaf(e00, v0[c], fmaf(e10, v1[c], fmaf(e01, v2[c], e11 * v3[c]))));
    }

    const float inv = 1.0f / s;
    uint4 ru;
    ru.x = (uint)f2bf(o[0] * inv) | ((uint)f2bf(o[1] * inv) << 16);
    ru.y = (uint)f2bf(o[2] * inv) | ((uint)f2bf(o[3] * inv) << 16);
    ru.z = (uint)f2bf(o[4] * inv) | ((uint)f2bf(o[5] * inv) << 16);
    ru.w = (uint)f2bf(o[6] * inv) | ((uint)f2bf(o[7] * inv) << 16);
    *(uint4*)(attnb + (size_t)token * DMODEL + h * HDIM + lc * 8) = ru;
}

// ---------------------------------------------------------------------------
extern "C" void kernel_launch(void* const* d_in, const int* in_sizes, int n_in,
                              void* d_out, int out_size, void* d_ws, size_t ws_size,
                              hipStream_t stream) {
    const float* x    = (const float*)d_in[0];
    const float* Wq   = (const float*)d_in[1];
    const float* bq   = (const float*)d_in[2];
    const float* Woff = (const float*)d_in[3];
    const float* boff = (const float*)d_in[4];
    const float* Wkv  = (const float*)d_in[5];
    const float* bkv  = (const float*)d_in[6];
    const float* Wout = (const float*)d_in[7];
    const float* bout = (const float*)d_in[8];

    // workspace layout (~68 MB)
    ushort* xb    = (ushort*)d_ws;                         // 6,553,600 (aliased by attnb)
    ushort* qb    = xb + (size_t)MTOT * DMODEL;            // 6,553,600
    float*  off   = (float*)(qb + (size_t)MTOT * DMODEL);  // 3,686,400 fp32
    ushort* kfb   = (ushort*)(off + (size_t)MTOT * 144);   // 6,553,600
    ushort* vfb   = kfb + (size_t)MTOT * DMODEL;           // 6,553,600
    ushort* wqb   = vfb + (size_t)MTOT * DMODEL;           // 65,536
    ushort* woffb = wqb + 65536;                           // 36,864
    ushort* wkvb  = woffb + 36864;                         // 131,072
    ushort* woutb = wkvb + 131072;                         // 65,536
    ushort* attnb = xb;   // xb dead after the kv GEMM

    cast_all<<<dim3(6692), dim3(256), 0, stream>>>(x, Wq, Woff, Wkv, Wout,
                                                   xb, wqb, woffb, wkvb, woutb);

    gemm_bf16<0><<<dim3(2, 200), dim3(256), 0, stream>>>(xb, wqb, bq, qb, nullptr, 256);
    gemm_bf16<1><<<dim3(2, 200), dim3(256), 0, stream>>>(xb, woffb, boff, off, nullptr, 144);
    gemm_bf16<2><<<dim3(4, 200), dim3(256), 0, stream>>>(xb, wkvb, bkv, kfb, vfb, 512);
    deform_attn<<<dim3(3200), dim3(256), 0, stream>>>(qb, off, kfb, vfb, attnb);
    gemm_bf16<3><<<dim3(2, 200), dim3(256), 0, stream>>>(attnb, woutb, bout, d_out, nullptr, 256);
}